// Round 2
// baseline (1457.611 us; speedup 1.0000x reference)
//
#include <hip/hip_runtime.h>
#include <hip/hip_bf16.h>

typedef __hip_bfloat16 bf16;
typedef __attribute__((ext_vector_type(8))) short short8;
typedef __attribute__((ext_vector_type(4))) float floatx4;

#define K_DIM 4096
#define N_DIM 4096
#define M_DIM 16384
#define RANK  64

#define BM 128
#define BN 128
#define BK 32

// ---------------------------------------------------------------------------
// fp32 -> bf16 bulk convert (x: [16384,4096]). 8 elements/thread,
// float4 x2 in, short8 out. ~400 MB traffic -> ~65 us.
// ---------------------------------------------------------------------------
__global__ __launch_bounds__(256) void cvt_x_kernel(
    const float4* __restrict__ in, short8* __restrict__ out)
{
    const int i = blockIdx.x * 256 + threadIdx.x;
    const float4 a = in[2 * i];
    const float4 b = in[2 * i + 1];
    bf16 t[8];
    t[0] = __float2bfloat16(a.x); t[1] = __float2bfloat16(a.y);
    t[2] = __float2bfloat16(a.z); t[3] = __float2bfloat16(a.w);
    t[4] = __float2bfloat16(b.x); t[5] = __float2bfloat16(b.y);
    t[6] = __float2bfloat16(b.z); t[7] = __float2bfloat16(b.w);
    out[i] = *(const short8*)t;
}

// ---------------------------------------------------------------------------
// W_eff[n,k] = W[n,k] + sum_r p[n,r]*lam[r]*q[r,k] - sum_r bp[n,r]*blam[r]*bq[r,k]
// All inputs fp32, fp32 accumulate, bf16 output. Thread = one k column,
// 8 consecutive n rows. q/bq coalesced; p/bp/lam block-uniform.
// ---------------------------------------------------------------------------
__global__ __launch_bounds__(256) void prep_weff_kernel(
    const float* __restrict__ W, const float* __restrict__ q,
    const float* __restrict__ p, const float* __restrict__ lam,
    const float* __restrict__ bq, const float* __restrict__ bp,
    const float* __restrict__ blam, bf16* __restrict__ Weff)
{
    const int k  = blockIdx.x * 256 + threadIdx.x;
    const int n0 = blockIdx.y * 8;
    float acc[8];
#pragma unroll
    for (int i = 0; i < 8; ++i) acc[i] = 0.0f;

    for (int r = 0; r < RANK; ++r) {
        const float qlv  = lam[r]  * q [r * K_DIM + k];
        const float bqlv = blam[r] * bq[r * K_DIM + k];
#pragma unroll
        for (int i = 0; i < 8; ++i) {
            acc[i] += p [(n0 + i) * RANK + r] * qlv;
            acc[i] -= bp[(n0 + i) * RANK + r] * bqlv;
        }
    }
#pragma unroll
    for (int i = 0; i < 8; ++i) {
        const size_t idx = (size_t)(n0 + i) * K_DIM + k;
        Weff[idx] = __float2bfloat16(W[idx] + acc[i]);
    }
}

// ---------------------------------------------------------------------------
// C[M,N] = A[M,K] * B[N,K]^T. A,B bf16 (pre-converted), C fp32 out.
// m97-structure: 128x128 tile, BK=32, 4 waves 2x2, each wave 64x64 via
// 4x4 mfma_f32_16x16x32_bf16. global_load_lds width=16 staging; LDS tile
// row-major [row][32] contiguous in lane-segment order (no padding —
// required by the wave-uniform-base + lane*16 scatter rule).
// ---------------------------------------------------------------------------
__global__ __launch_bounds__(256) void gemm_bt_kernel(
    const bf16* __restrict__ A, const bf16* __restrict__ B, float* __restrict__ C)
{
    __shared__ __align__(16) bf16 As[BM * BK];
    __shared__ __align__(16) bf16 Bs[BN * BK];

    const int tid  = threadIdx.x;
    const int lane = tid & 63;
    const int wave = tid >> 6;   // 0..3
    const int wm   = wave >> 1;  // 0..1
    const int wn   = wave & 1;   // 0..1

    const int tile_m = blockIdx.y * BM;
    const int tile_n = blockIdx.x * BN;

    // staging: thread t owns 16B segments t and t+256 of each 8 KiB tile.
    const int r0 = tid >> 2;
    const int c0 = (tid & 3) * 8;

    const bf16* Ag0 = A + (size_t)(tile_m + r0)      * K_DIM + c0;
    const bf16* Ag1 = A + (size_t)(tile_m + r0 + 64) * K_DIM + c0;
    const bf16* Bg0 = B + (size_t)(tile_n + r0)      * K_DIM + c0;
    const bf16* Bg1 = B + (size_t)(tile_n + r0 + 64) * K_DIM + c0;

    char* ldsA = (char*)As;
    char* ldsB = (char*)Bs;
    const int wb0 = wave * 1024;         // segments wave*64 + lane
    const int wb1 = 4096 + wave * 1024;  // segments 256 + wave*64 + lane

    floatx4 acc[4][4];
#pragma unroll
    for (int i = 0; i < 4; ++i)
#pragma unroll
        for (int j = 0; j < 4; ++j)
            acc[i][j] = (floatx4){0.f, 0.f, 0.f, 0.f};

    // A-frag: lane holds A[m=lane&15][k=(lane>>4)*8 + 0..7]
    const int mr   = lane & 15;
    const int krow = (lane >> 4) * 8;
    const bf16* Asf = As + (wm * 64 + mr) * BK + krow;
    const bf16* Bsf = Bs + (wn * 64 + mr) * BK + krow;

    for (int k0 = 0; k0 < K_DIM; k0 += BK) {
        __builtin_amdgcn_global_load_lds(
            (const __attribute__((address_space(1))) void*)(Ag0 + k0),
            (__attribute__((address_space(3))) void*)(ldsA + wb0), 16, 0, 0);
        __builtin_amdgcn_global_load_lds(
            (const __attribute__((address_space(1))) void*)(Ag1 + k0),
            (__attribute__((address_space(3))) void*)(ldsA + wb1), 16, 0, 0);
        __builtin_amdgcn_global_load_lds(
            (const __attribute__((address_space(1))) void*)(Bg0 + k0),
            (__attribute__((address_space(3))) void*)(ldsB + wb0), 16, 0, 0);
        __builtin_amdgcn_global_load_lds(
            (const __attribute__((address_space(1))) void*)(Bg1 + k0),
            (__attribute__((address_space(3))) void*)(ldsB + wb1), 16, 0, 0);
        __syncthreads();  // drains vmcnt(0) -> staging visible

        short8 af[4], bfr[4];
#pragma unroll
        for (int i = 0; i < 4; ++i) af[i]  = *(const short8*)(Asf + i * 16 * BK);
#pragma unroll
        for (int j = 0; j < 4; ++j) bfr[j] = *(const short8*)(Bsf + j * 16 * BK);

#pragma unroll
        for (int i = 0; i < 4; ++i)
#pragma unroll
            for (int j = 0; j < 4; ++j)
                acc[i][j] = __builtin_amdgcn_mfma_f32_16x16x32_bf16(
                    af[i], bfr[j], acc[i][j], 0, 0, 0);
        __syncthreads();  // before next iter overwrites LDS
    }

    // C/D layout (verified m89/m91): col = lane&15, row = (lane>>4)*4 + reg
    const int row0 = tile_m + wm * 64 + (lane >> 4) * 4;
    const int col0 = tile_n + wn * 64 + (lane & 15);
#pragma unroll
    for (int i = 0; i < 4; ++i)
#pragma unroll
        for (int j = 0; j < 4; ++j)
#pragma unroll
            for (int rr = 0; rr < 4; ++rr)
                C[(size_t)(row0 + i * 16 + rr) * N_DIM + (col0 + j * 16)] =
                    acc[i][j][rr];
}

extern "C" void kernel_launch(void* const* d_in, const int* in_sizes, int n_in,
                              void* d_out, int out_size, void* d_ws, size_t ws_size,
                              hipStream_t stream)
{
    const float* x    = (const float*)d_in[0];  // [4,4096,4096] fp32
    const float* Worg = (const float*)d_in[1];  // [4096,4096]
    const float* qw   = (const float*)d_in[2];  // [64,4096]
    const float* pw   = (const float*)d_in[3];  // [4096,64]
    const float* lam  = (const float*)d_in[4];  // [64]
    const float* bqw  = (const float*)d_in[5];
    const float* bpw  = (const float*)d_in[6];
    const float* blam = (const float*)d_in[7];
    float* out = (float*)d_out;                 // [16384,4096] fp32

    // ws layout: [x_bf16: 16384*4096*2 = 134217728 B][Weff: 4096*4096*2 = 33554432 B]
    bf16* x_bf = (bf16*)d_ws;
    bf16* Weff = (bf16*)((char*)d_ws + (size_t)M_DIM * K_DIM * 2);

    // convert x to bf16: 67108864 elements / 8 per thread / 256 per block
    cvt_x_kernel<<<dim3((M_DIM * K_DIM) / (8 * 256)), 256, 0, stream>>>(
        (const float4*)x, (short8*)x_bf);

    prep_weff_kernel<<<dim3(K_DIM / 256, N_DIM / 8), 256, 0, stream>>>(
        Worg, qw, pw, lam, bqw, bpw, blam, Weff);

    gemm_bt_kernel<<<dim3(N_DIM / BN, M_DIM / BM), 256, 0, stream>>>(x_bf, Weff, out);
}